// Round 4
// baseline (88.496 us; speedup 1.0000x reference)
//
#include <hip/hip_runtime.h>

// Problem constants (from reference setup_inputs / OUTPUT_LENGTH)
#define B_SZ 16
#define N_SZ 512
#define C_SZ 512
#define L_SZ 2048
#define ROW4 (C_SZ / 4)                      // 128 float4 per row

typedef float f32x4 __attribute__((ext_vector_type(4)));

// ---------------------------------------------------------------------------
// Kernel 1: per-batch duration cumsum -> timestep->phoneme index map.
// grid = 16 blocks x 512 threads. Runs ONCE (R3 showed per-block prologue
// recomputation costs ~2 us/generation; this removes it from the hot kernel).
// ---------------------------------------------------------------------------
__global__ __launch_bounds__(N_SZ) void build_idx_kernel(
    const float* __restrict__ log_durations,  // (B, N, 1)
    int* __restrict__ idx)                    // (B, L) out: phoneme index or -1
{
    __shared__ int wsum[8];
    const int b    = blockIdx.x;
    const int n    = threadIdx.x;
    const int lane = n & 63;
    const int w    = n >> 6;

    // dur = floor(2^ld + 1e-4) * (ld > 0), matching the reference math.
    const float ld = log_durations[b * N_SZ + n];
    int dur = 0;
    if (ld > 0.0f) dur = (int)floorf(exp2f(ld) + 1e-4f);

    // Inclusive scan within the 64-lane wave.
    int scan = dur;
    #pragma unroll
    for (int o = 1; o < 64; o <<= 1) {
        int v = __shfl_up(scan, o, 64);
        if (lane >= o) scan += v;
    }
    if (lane == 63) wsum[w] = scan;
    __syncthreads();

    int base = 0, total = 0;
    #pragma unroll
    for (int i = 0; i < 8; ++i) {
        const int s = wsum[i];
        if (i < w) base += s;
        total += s;
    }
    const int end   = base + scan;
    const int start = end - dur;

    // Scatter: idx[b, start..end) = n (durations are tiny: mostly 0-3).
    if (start < L_SZ) {
        const int e = min(end, L_SZ);
        for (int t = start; t < e; ++t) idx[b * L_SZ + t] = n;
    }
    // Tail: idx[b, total..L) = -1
    const int tmin = min(total, L_SZ);
    for (int t = tmin + n; t < L_SZ; t += N_SZ) idx[b * L_SZ + t] = -1;
}

// ---------------------------------------------------------------------------
// Kernel 2: pure streaming gather. 2048 blocks x 256 threads, each block owns
// 16 contiguous output rows (32 KB contiguous writes). No LDS, no barriers.
// XCD-bijective swizzle: each XCD gets 2 whole batches (2 MB enc in its L2).
// idx reads are row-uniform -> L1 broadcast.
// ---------------------------------------------------------------------------
#define G_THREADS 256
#define G_ROWS 16
#define G_BLKS_PER_BATCH (L_SZ / G_ROWS)       // 128
#define G_NBLOCKS (B_SZ * G_BLKS_PER_BATCH)    // 2048

__global__ __launch_bounds__(G_THREADS) void gather_kernel(
    const f32x4* __restrict__ enc,   // (B, N, C) as float4
    const int*   __restrict__ idx,   // (B, L)
    f32x4*       __restrict__ out)   // (B, L, C) as float4
{
    const int bid = blockIdx.x;
    const int swz = (bid & 7) * (G_NBLOCKS / 8) + (bid >> 3);
    const int b   = swz >> 7;                              // / G_BLKS_PER_BATCH
    const int l0  = (swz & (G_BLKS_PER_BATCH - 1)) * G_ROWS;

    const int tid = threadIdx.x;
    const int c4  = tid & (ROW4 - 1);
    const int rh  = tid >> 7;            // 0/1: two rows per pass

    const f32x4* enc_b = enc + (size_t)b * N_SZ * ROW4;
    f32x4*       out_b = out + ((size_t)b * L_SZ + l0) * ROW4;
    const int*   idx_b = idx + b * L_SZ + l0;

    #pragma unroll
    for (int rr = 0; rr < 8; ++rr) {
        const int r = rr * 2 + rh;
        const int p = idx_b[r];          // row-uniform -> L1 broadcast
        f32x4 v = (f32x4)(0.0f);
        if (p >= 0) v = enc_b[p * ROW4 + c4];
        out_b[r * ROW4 + c4] = v;
    }
}

extern "C" void kernel_launch(void* const* d_in, const int* in_sizes, int n_in,
                              void* d_out, int out_size, void* d_ws, size_t ws_size,
                              hipStream_t stream) {
    const float* enc = (const float*)d_in[0];   // (16, 512, 512) fp32
    const float* ld  = (const float*)d_in[1];   // (16, 512, 1)  fp32
    float* out       = (float*)d_out;           // (16, 2048, 512) fp32
    int* idx         = (int*)d_ws;              // B*L ints = 128 KB scratch

    build_idx_kernel<<<B_SZ, N_SZ, 0, stream>>>(ld, idx);
    gather_kernel<<<G_NBLOCKS, G_THREADS, 0, stream>>>(
        (const f32x4*)enc, idx, (f32x4*)out);
}

// Round 5
// 84.922 us; speedup vs baseline: 1.0421x; 1.0421x over previous
//
#include <hip/hip_runtime.h>

// Problem constants (from reference setup_inputs / OUTPUT_LENGTH)
#define B_SZ 16
#define N_SZ 512
#define C_SZ 512
#define L_SZ 2048
#define ROW4 (C_SZ / 4)              // 128 float4 per output row
#define TOTAL4 (B_SZ * L_SZ * ROW4)  // 4,194,304 float4 elements

// ---------------------------------------------------------------------------
// Kernel 1: per-batch duration cumsum -> timestep->phoneme index map.
// grid = B_SZ blocks, block = N_SZ threads. One barrier total (wave-shuffle
// scan inside each 64-lane wave, tiny LDS combine across the 8 waves).
// ---------------------------------------------------------------------------
__global__ __launch_bounds__(N_SZ) void build_idx_kernel(
    const float* __restrict__ log_durations,  // (B, N, 1)
    int* __restrict__ idx)                    // (B, L) out: phoneme index or -1
{
    __shared__ int wsum[8];
    const int b    = blockIdx.x;
    const int n    = threadIdx.x;
    const int lane = n & 63;
    const int w    = n >> 6;

    // dur = floor(2^ld + 1e-4) * (ld > 0), matching the reference math.
    const float ld = log_durations[b * N_SZ + n];
    int dur = 0;
    if (ld > 0.0f) dur = (int)floorf(exp2f(ld) + 1e-4f);

    // Inclusive scan within the 64-lane wave (no barriers).
    int scan = dur;
    #pragma unroll
    for (int o = 1; o < 64; o <<= 1) {
        int v = __shfl_up(scan, o, 64);
        if (lane >= o) scan += v;
    }
    if (lane == 63) wsum[w] = scan;
    __syncthreads();

    // Add exclusive prefix of wave totals; also grab grand total.
    int base = 0, total = 0;
    #pragma unroll
    for (int i = 0; i < 8; ++i) {
        const int s = wsum[i];     // LDS broadcast, conflict-free
        if (i < w) base += s;
        total += s;
    }
    const int end   = base + scan;
    const int start = end - dur;

    // Scatter: idx[b, start..end) = n  (clamped to L). Durations are small
    // (floor(2^N(0,1)) -> mostly 1-3), so this loop is short.
    if (start < L_SZ) {
        const int e = min(end, L_SZ);
        for (int t = start; t < e; ++t) idx[b * L_SZ + t] = n;
    }

    // Tail: idx[b, total..L) = -1
    const int tmin = min(total, L_SZ);
    for (int t = tmin + n; t < L_SZ; t += N_SZ) idx[b * L_SZ + t] = -1;
}

// ---------------------------------------------------------------------------
// Kernel 2: out[b, l, :] = (p >= 0) ? enc[b, p, :] : 0
// grid = 2048 blocks x 256 threads; each thread does exactly 8 independent
// float4 copy iterations (stride 2048*256), fully unrolled for MLP.
// Strided sweep: all resident blocks advance through the output in address
// order together -> contiguous instantaneous write front (best DRAM page
// locality). Measured best shape (R0/R2/R3/R4 comparison).
// ---------------------------------------------------------------------------
#define G_BLOCKS 2048
#define G_THREADS 256
#define G_STRIDE (G_BLOCKS * G_THREADS)        // 524,288
#define G_ITERS (TOTAL4 / G_STRIDE)            // 8 exactly

__global__ __launch_bounds__(G_THREADS) void gather_kernel(
    const float4* __restrict__ enc,   // (B, N, C) as float4
    const int*    __restrict__ idx,   // (B, L)
    float4*       __restrict__ out)   // (B, L, C) as float4
{
    const int g0 = blockIdx.x * G_THREADS + threadIdx.x;
    #pragma unroll
    for (int it = 0; it < G_ITERS; ++it) {
        const int g   = g0 + it * G_STRIDE;
        const int row = g >> 7;        // /ROW4
        const int b   = row >> 11;     // /L_SZ
        const int c4  = g & (ROW4 - 1);
        const int p   = idx[row];      // wave-uniform per half-row, L1/L2 hit
        float4 v = make_float4(0.f, 0.f, 0.f, 0.f);
        if (p >= 0) v = enc[(size_t)((b << 9) + p) * ROW4 + c4];
        out[g] = v;
    }
}

extern "C" void kernel_launch(void* const* d_in, const int* in_sizes, int n_in,
                              void* d_out, int out_size, void* d_ws, size_t ws_size,
                              hipStream_t stream) {
    const float* enc = (const float*)d_in[0];          // (16, 512, 512) fp32
    const float* ld  = (const float*)d_in[1];          // (16, 512, 1)  fp32
    float* out       = (float*)d_out;                  // (16, 2048, 512) fp32
    int* idx         = (int*)d_ws;                     // B*L ints = 128 KB scratch

    build_idx_kernel<<<B_SZ, N_SZ, 0, stream>>>(ld, idx);
    gather_kernel<<<G_BLOCKS, G_THREADS, 0, stream>>>(
        (const float4*)enc, idx, (float4*)out);
}